// Round 3
// baseline (768.162 us; speedup 1.0000x reference)
//
#include <hip/hip_runtime.h>
#include <hip/hip_bf16.h>

#define N_NODES 50000
#define N_EDGES 800000
#define N_FEAT  64
#define UNITS   128
#define OUT_C   (2 * UNITS)   // 256

// ---------------------------------------------------------------------------
// Kernel 0: detect int64 vs int32 edge_index (odd words all zero => int64).
// ---------------------------------------------------------------------------
__global__ void detect_idx_dtype(const void* __restrict__ ei_raw,
                                 int* __restrict__ flag)
{
    const int* p = (const int*)ei_raw;
    int v = p[2 * threadIdx.x + 1];
    unsigned long long b = __ballot(v == 0);
    if (threadIdx.x == 0) *flag = (b == ~0ull) ? 1 : 0;
}

// ---------------------------------------------------------------------------
// Kernel 1: degree histogram. One thread per edge, int atomic on deg[row].
// ---------------------------------------------------------------------------
__global__ __launch_bounds__(256) void degree_hist(
    const void* __restrict__ ei_raw, const int* __restrict__ flag,
    int* __restrict__ deg)
{
    int e = blockIdx.x * blockDim.x + threadIdx.x;
    if (e >= N_EDGES) return;
    int row;
    if (*flag) row = (int)((const long long*)ei_raw)[e];
    else       row = ((const int*)ei_raw)[e];
    row = min(max(row, 0), N_NODES - 1);
    atomicAdd(&deg[row], 1);
}

// ---------------------------------------------------------------------------
// Kernel 2: exclusive scan of deg[50000] -> offsets[50001]. Single block,
// 1024 threads x 49 elements, Hillis-Steele over per-thread partials.
// ---------------------------------------------------------------------------
#define SCAN_T 1024
#define PER_T  49   // ceil(50000/1024)

__global__ __launch_bounds__(SCAN_T) void scan_offsets(
    const int* __restrict__ deg, int* __restrict__ offsets)
{
    __shared__ int ps[SCAN_T];
    const int t = threadIdx.x;
    int lo = t * PER_T;
    int hi = min(lo + PER_T, N_NODES);
    int s = 0;
    for (int i = lo; i < hi; ++i) s += deg[i];
    ps[t] = s;
    __syncthreads();
    for (int off = 1; off < SCAN_T; off <<= 1) {
        int v = (t >= off) ? ps[t - off] : 0;
        __syncthreads();
        ps[t] += v;
        __syncthreads();
    }
    int pre = (t > 0) ? ps[t - 1] : 0;   // exclusive prefix
    for (int i = lo; i < hi; ++i) { offsets[i] = pre; pre += deg[i]; }
    if (t == SCAN_T - 1) offsets[N_NODES] = pre;   // = 800000
}

// ---------------------------------------------------------------------------
// Kernel 3: CSR fill. pos = cursor[row]++; adj[offsets[row]+pos] = col.
// ---------------------------------------------------------------------------
__global__ __launch_bounds__(256) void csr_fill(
    const void* __restrict__ ei_raw, const int* __restrict__ flag,
    const int* __restrict__ offsets, int* __restrict__ cursor,
    int* __restrict__ adj)
{
    int e = blockIdx.x * blockDim.x + threadIdx.x;
    if (e >= N_EDGES) return;
    int row, col;
    if (*flag) {
        row = (int)((const long long*)ei_raw)[e];
        col = (int)((const long long*)ei_raw)[(long long)N_EDGES + e];
    } else {
        row = ((const int*)ei_raw)[e];
        col = ((const int*)ei_raw)[N_EDGES + e];
    }
    row = min(max(row, 0), N_NODES - 1);
    col = min(max(col, 0), N_NODES - 1);
    int pos = atomicAdd(&cursor[row], 1);
    adj[offsets[row] + pos] = col;
}

// ---------------------------------------------------------------------------
// Kernel 4: gather-aggregate. One wave per node; lane = feature. Plain adds,
// no atomics. Neighbor index loads are wave-uniform (broadcast).
// ---------------------------------------------------------------------------
__global__ __launch_bounds__(256) void aggregate(
    const float* __restrict__ x, const int* __restrict__ offsets,
    const int* __restrict__ adj, float* __restrict__ mean)
{
    int wv   = (blockIdx.x * blockDim.x + threadIdx.x) >> 6;
    int lane = threadIdx.x & 63;
    if (wv >= N_NODES) return;
    int o0 = offsets[wv], o1 = offsets[wv + 1];
    float s = 0.f;
    int j = o0;
    for (; j + 4 <= o1; j += 4) {
        int c0 = adj[j], c1 = adj[j + 1], c2 = adj[j + 2], c3 = adj[j + 3];
        float v0 = x[(long long)c0 * N_FEAT + lane];
        float v1 = x[(long long)c1 * N_FEAT + lane];
        float v2 = x[(long long)c2 * N_FEAT + lane];
        float v3 = x[(long long)c3 * N_FEAT + lane];
        s += v0; s += v1; s += v2; s += v3;
    }
    for (; j < o1; ++j) s += x[(long long)adj[j] * N_FEAT + lane];
    float d = (float)(o1 - o0);
    mean[(long long)wv * N_FEAT + lane] = s / fmaxf(d, 1.0f);
}

// ---------------------------------------------------------------------------
// Kernel 5: fused dual GEMM [N,64]x[64,128]x2 + concat + bias + relu.
// 512 threads, 64 rows/block. Thread (cg=t&63, rg=t>>6) computes 8 rows x
// 4 cols. LDS: W[64][256] (64KB) + A[64][2][64] (32KB; [.][0]=mean,
// [.][1]=x). W read: per-lane contiguous ds_read_b128 (1KB/wave,
// conflict-free). A read: wave-broadcast b128 (2 distinct addrs/wave).
// ---------------------------------------------------------------------------
#define G_ROWS 64

__global__ __launch_bounds__(512) void fused_gemm(
    const float* __restrict__ mean,   // [N][64]
    const float* __restrict__ x,      // [N][64]
    const float* __restrict__ wn,     // [64][128]
    const float* __restrict__ wsf,    // [64][128]
    const float* __restrict__ bias,   // [256]
    float* __restrict__ out)          // [N][256]
{
    __shared__ float W[N_FEAT * OUT_C];        // 64 KB
    __shared__ float A[G_ROWS][2][N_FEAT];     // 32 KB

    const int t = threadIdx.x;
    const int row0 = blockIdx.x * G_ROWS;

    // Stage W: 4096 float4, 8 per thread.
    for (int i = t; i < (N_FEAT * OUT_C) / 4; i += 512) {
        int fl = i * 4;
        int k = fl >> 8;
        int u = fl & 255;
        float4 v;
        if (u < UNITS) v = *(const float4*)&wn[k * UNITS + u];
        else           v = *(const float4*)&wsf[k * UNITS + (u - UNITS)];
        *(float4*)&W[fl] = v;
    }
    // Stage A: 2048 float4, 4 per thread.
    for (int i = t; i < (G_ROWS * 2 * N_FEAT) / 4; i += 512) {
        int fl = i * 4;
        int r = fl >> 7;            // /128
        int rem = fl & 127;
        int half = rem >> 6;
        int k = rem & 63;
        int grow = row0 + r;
        float4 v = make_float4(0.f, 0.f, 0.f, 0.f);
        if (grow < N_NODES) {
            v = half ? *(const float4*)&x[(long long)grow * N_FEAT + k]
                     : *(const float4*)&mean[(long long)grow * N_FEAT + k];
        }
        *(float4*)&A[r][half][k] = v;
    }
    __syncthreads();

    const int cg = t & 63;          // lane: cols [cg*4, cg*4+4)
    const int rg = t >> 6;          // 0..7: rows [rg*8, rg*8+8)
    const int c0 = cg * 4;
    const int half = (cg >= 32) ? 1 : 0;   // cols<128 -> mean, else x

    float4 acc[8];
    #pragma unroll
    for (int r = 0; r < 8; ++r) acc[r] = make_float4(0.f, 0.f, 0.f, 0.f);

    #pragma unroll
    for (int kk = 0; kk < N_FEAT; kk += 4) {
        float4 a[8];
        #pragma unroll
        for (int r = 0; r < 8; ++r)
            a[r] = *(const float4*)&A[rg * 8 + r][half][kk];
        #pragma unroll
        for (int k4 = 0; k4 < 4; ++k4) {
            float4 w = *(const float4*)&W[(kk + k4) * OUT_C + c0];
            #pragma unroll
            for (int r = 0; r < 8; ++r) {
                float av = ((const float*)&a[r])[k4];
                acc[r].x += av * w.x;
                acc[r].y += av * w.y;
                acc[r].z += av * w.z;
                acc[r].w += av * w.w;
            }
        }
    }

    float4 b = *(const float4*)&bias[c0];
    #pragma unroll
    for (int r = 0; r < 8; ++r) {
        int grow = row0 + rg * 8 + r;
        if (grow >= N_NODES) continue;
        float4 o;
        o.x = fmaxf(acc[r].x + b.x, 0.f);
        o.y = fmaxf(acc[r].y + b.y, 0.f);
        o.z = fmaxf(acc[r].z + b.z, 0.f);
        o.w = fmaxf(acc[r].w + b.w, 0.f);
        *(float4*)&out[(long long)grow * OUT_C + c0] = o;
    }
}

// ---------------------------------------------------------------------------
extern "C" void kernel_launch(void* const* d_in, const int* in_sizes, int n_in,
                              void* d_out, int out_size, void* d_ws, size_t ws_size,
                              hipStream_t stream) {
    const float* x    = (const float*)d_in[0];
    const void*  ei   = d_in[1];                 // int64 or int32 [2][E]
    const float* wn   = (const float*)d_in[2];
    const float* wsf  = (const float*)d_in[3];
    const float* bias = (const float*)d_in[4];
    float*       out  = (float*)d_out;

    // Workspace layout (~16.6 MB):
    float* mean   = (float*)d_ws;                       // 50000*64 f32
    int*   adj    = (int*)(mean + (size_t)N_NODES * N_FEAT);  // 800000
    int*   deg    = adj + N_EDGES;                      // 50000
    int*   cursor = deg + N_NODES;                      // 50000
    int*   offs   = cursor + N_NODES;                   // 50001
    int*   flag   = offs + (N_NODES + 1);               // 1

    // Zero only deg + cursor (contiguous 100000 ints).
    hipMemsetAsync(deg, 0, (size_t)2 * N_NODES * sizeof(int), stream);

    detect_idx_dtype<<<1, 64, 0, stream>>>(ei, flag);

    int eblocks = (N_EDGES + 255) / 256;                // 3125
    degree_hist<<<eblocks, 256, 0, stream>>>(ei, flag, deg);
    scan_offsets<<<1, SCAN_T, 0, stream>>>(deg, offs);
    csr_fill<<<eblocks, 256, 0, stream>>>(ei, flag, offs, cursor, adj);

    int ablocks = (N_NODES * 64 + 255) / 256;           // 12500 (wave/node)
    aggregate<<<ablocks, 256, 0, stream>>>(x, offs, adj, mean);

    int gblocks = (N_NODES + G_ROWS - 1) / G_ROWS;      // 782
    fused_gemm<<<gblocks, 512, 0, stream>>>(mean, x, wn, wsf, bias, out);
}

// Round 4
// 698.104 us; speedup vs baseline: 1.1004x; 1.1004x over previous
//
#include <hip/hip_runtime.h>
#include <hip/hip_bf16.h>

#define N_NODES 50000
#define N_EDGES 800000
#define N_FEAT  64
#define UNITS   128
#define OUT_C   256
#define MAXDEG  64

// ---------------------------------------------------------------------------
// Kernel 0: detect int64 vs int32 edge_index (odd words all zero => int64).
// ---------------------------------------------------------------------------
__global__ void detect_idx_dtype(const void* __restrict__ ei_raw,
                                 int* __restrict__ flag)
{
    const int* p = (const int*)ei_raw;
    int v = p[2 * threadIdx.x + 1];
    unsigned long long b = __ballot(v == 0);
    if (threadIdx.x == 0) *flag = (b == ~0ull) ? 1 : 0;
}

// ---------------------------------------------------------------------------
// Kernel 1: bucket fill. adj[row][pos] = col, pos = cursor[row]++.
// Fixed-stride buckets (MAXDEG=64): no histogram, no scan. Max degree of
// Binomial(800k, 1/50k) is ~38; pos clamped for safety. col < 65536 so
// uint16 storage (6.4 MB).
// ---------------------------------------------------------------------------
__global__ __launch_bounds__(256) void bucket_fill(
    const void* __restrict__ ei_raw, const int* __restrict__ flag,
    int* __restrict__ cursor, unsigned short* __restrict__ adj)
{
    int e = blockIdx.x * blockDim.x + threadIdx.x;
    if (e >= N_EDGES) return;
    int row, col;
    if (*flag) {
        row = (int)((const long long*)ei_raw)[e];
        col = (int)((const long long*)ei_raw)[(long long)N_EDGES + e];
    } else {
        row = ((const int*)ei_raw)[e];
        col = ((const int*)ei_raw)[N_EDGES + e];
    }
    row = min(max(row, 0), N_NODES - 1);
    col = min(max(col, 0), N_NODES - 1);
    int pos = atomicAdd(&cursor[row], 1);
    if (pos < MAXDEG) adj[row * MAXDEG + pos] = (unsigned short)col;
}

// ---------------------------------------------------------------------------
// Kernel 2: gather-aggregate. One wave per node; lane = feature. Each
// x-row load is a fully-coalesced 256B wave read; 4 independent partial
// sums for load ILP. No atomics.
// ---------------------------------------------------------------------------
__global__ __launch_bounds__(256) void aggregate(
    const float* __restrict__ x, const int* __restrict__ cursor,
    const unsigned short* __restrict__ adj, float* __restrict__ mean)
{
    int wv   = (blockIdx.x * blockDim.x + threadIdx.x) >> 6;
    int lane = threadIdx.x & 63;
    if (wv >= N_NODES) return;
    int deg = min(cursor[wv], MAXDEG);
    const unsigned short* a = &adj[wv * MAXDEG];

    float s0 = 0.f, s1 = 0.f, s2 = 0.f, s3 = 0.f;
    int j = 0;
    for (; j + 4 <= deg; j += 4) {
        ushort4 n = *(const ushort4*)&a[j];     // wave-uniform 8B load
        float v0 = x[(int)n.x * N_FEAT + lane];
        float v1 = x[(int)n.y * N_FEAT + lane];
        float v2 = x[(int)n.z * N_FEAT + lane];
        float v3 = x[(int)n.w * N_FEAT + lane];
        s0 += v0; s1 += v1; s2 += v2; s3 += v3;
    }
    for (; j < deg; ++j) s0 += x[(int)a[j] * N_FEAT + lane];
    float s = (s0 + s1) + (s2 + s3);
    mean[wv * N_FEAT + lane] = s / fmaxf((float)deg, 1.0f);
}

// ---------------------------------------------------------------------------
// Kernel 3: half-GEMM [64 rows, 64k] x [64][128] + bias + relu.
// blockIdx.y = 0: mean @ wn -> out cols 0..127
// blockIdx.y = 1: x    @ wsf -> out cols 128..255
// 512 threads; thread (cg=t&31 -> 4 cols, rg=t>>5 -> 4 rows). LDS 48KB
// (W 32KB + A 16KB) -> 3 blocks/CU. NO register arrays, NO address-of on
// registers: named float4s with member access only (round-3 scratch-spill
// post-mortem).
// ---------------------------------------------------------------------------
#define FMA4(ACC, AV, W) \
    ACC.x += (AV) * (W).x; ACC.y += (AV) * (W).y; \
    ACC.z += (AV) * (W).z; ACC.w += (AV) * (W).w;

__global__ __launch_bounds__(512) void half_gemm(
    const float* __restrict__ mean,   // [N][64]
    const float* __restrict__ x,      // [N][64]
    const float* __restrict__ wn,     // [64][128]
    const float* __restrict__ wsf,    // [64][128]
    const float* __restrict__ bias,   // [256]
    float* __restrict__ out)          // [N][256]
{
    __shared__ float W[N_FEAT * UNITS];   // 32 KB
    __shared__ float A[64 * N_FEAT];      // 16 KB

    const int t = threadIdx.x;
    const int half = blockIdx.y;
    const int row0 = blockIdx.x * 64;
    const float* __restrict__ src  = half ? x   : mean;
    const float* __restrict__ wsrc = half ? wsf : wn;

    // Stage W: 8192 float4, 16 per thread, coalesced.
    {
        const float4* w4 = (const float4*)wsrc;
        float4* W4 = (float4*)W;
        #pragma unroll
        for (int i = 0; i < 16; ++i) W4[t + 512 * i] = w4[t + 512 * i];
    }
    // Stage A: 1024 float4, 2 per thread.
    {
        float4* A4 = (float4*)A;
        #pragma unroll
        for (int i = 0; i < 2; ++i) {
            int idx = t + 512 * i;
            int r = idx >> 4, k4 = idx & 15;
            int grow = row0 + r;
            float4 v = make_float4(0.f, 0.f, 0.f, 0.f);
            if (grow < N_NODES) v = *(const float4*)&src[grow * N_FEAT + k4 * 4];
            A4[idx] = v;
        }
    }
    __syncthreads();

    const int cg = t & 31;          // cols [cg*4, cg*4+4)
    const int r0 = (t >> 5) * 4;    // rows [r0, r0+4)
    const float4* W4 = (const float4*)W;   // [64][32]
    const float4* A4 = (const float4*)A;   // [64][16]

    float4 acc0 = make_float4(0.f, 0.f, 0.f, 0.f);
    float4 acc1 = acc0, acc2 = acc0, acc3 = acc0;

    #pragma unroll
    for (int kk = 0; kk < 16; ++kk) {
        float4 a0 = A4[(r0 + 0) * 16 + kk];
        float4 a1 = A4[(r0 + 1) * 16 + kk];
        float4 a2 = A4[(r0 + 2) * 16 + kk];
        float4 a3 = A4[(r0 + 3) * 16 + kk];
        float4 w;
        w = W4[(kk * 4 + 0) * 32 + cg];
        FMA4(acc0, a0.x, w) FMA4(acc1, a1.x, w) FMA4(acc2, a2.x, w) FMA4(acc3, a3.x, w)
        w = W4[(kk * 4 + 1) * 32 + cg];
        FMA4(acc0, a0.y, w) FMA4(acc1, a1.y, w) FMA4(acc2, a2.y, w) FMA4(acc3, a3.y, w)
        w = W4[(kk * 4 + 2) * 32 + cg];
        FMA4(acc0, a0.z, w) FMA4(acc1, a1.z, w) FMA4(acc2, a2.z, w) FMA4(acc3, a3.z, w)
        w = W4[(kk * 4 + 3) * 32 + cg];
        FMA4(acc0, a0.w, w) FMA4(acc1, a1.w, w) FMA4(acc2, a2.w, w) FMA4(acc3, a3.w, w)
    }

    float4 b = *(const float4*)&bias[half * UNITS + cg * 4];
    const int cbase = half * UNITS + cg * 4;
    int grow;
    float4 o;
    grow = row0 + r0 + 0;
    if (grow < N_NODES) {
        o.x = fmaxf(acc0.x + b.x, 0.f); o.y = fmaxf(acc0.y + b.y, 0.f);
        o.z = fmaxf(acc0.z + b.z, 0.f); o.w = fmaxf(acc0.w + b.w, 0.f);
        *(float4*)&out[(long long)grow * OUT_C + cbase] = o;
    }
    grow = row0 + r0 + 1;
    if (grow < N_NODES) {
        o.x = fmaxf(acc1.x + b.x, 0.f); o.y = fmaxf(acc1.y + b.y, 0.f);
        o.z = fmaxf(acc1.z + b.z, 0.f); o.w = fmaxf(acc1.w + b.w, 0.f);
        *(float4*)&out[(long long)grow * OUT_C + cbase] = o;
    }
    grow = row0 + r0 + 2;
    if (grow < N_NODES) {
        o.x = fmaxf(acc2.x + b.x, 0.f); o.y = fmaxf(acc2.y + b.y, 0.f);
        o.z = fmaxf(acc2.z + b.z, 0.f); o.w = fmaxf(acc2.w + b.w, 0.f);
        *(float4*)&out[(long long)grow * OUT_C + cbase] = o;
    }
    grow = row0 + r0 + 3;
    if (grow < N_NODES) {
        o.x = fmaxf(acc3.x + b.x, 0.f); o.y = fmaxf(acc3.y + b.y, 0.f);
        o.z = fmaxf(acc3.z + b.z, 0.f); o.w = fmaxf(acc3.w + b.w, 0.f);
        *(float4*)&out[(long long)grow * OUT_C + cbase] = o;
    }
}

// ---------------------------------------------------------------------------
extern "C" void kernel_launch(void* const* d_in, const int* in_sizes, int n_in,
                              void* d_out, int out_size, void* d_ws, size_t ws_size,
                              hipStream_t stream) {
    const float* x    = (const float*)d_in[0];
    const void*  ei   = d_in[1];                 // int64 or int32 [2][E]
    const float* wn   = (const float*)d_in[2];
    const float* wsf  = (const float*)d_in[3];
    const float* bias = (const float*)d_in[4];
    float*       out  = (float*)d_out;

    // Workspace (~19.4 MB): mean f32[50000*64] | adj u16[50000*64] |
    // cursor i32[50000] | flag i32.
    float*          mean   = (float*)d_ws;
    unsigned short* adj    = (unsigned short*)(mean + (size_t)N_NODES * N_FEAT);
    int*            cursor = (int*)(adj + (size_t)N_NODES * MAXDEG);
    int*            flag   = cursor + N_NODES;

    hipMemsetAsync(cursor, 0, (size_t)N_NODES * sizeof(int), stream);
    detect_idx_dtype<<<1, 64, 0, stream>>>(ei, flag);

    int eblocks = (N_EDGES + 255) / 256;                 // 3125
    bucket_fill<<<eblocks, 256, 0, stream>>>(ei, flag, cursor, adj);

    int ablocks = (N_NODES * 64 + 255) / 256;            // 12500 (wave/node)
    aggregate<<<ablocks, 256, 0, stream>>>(x, cursor, adj, mean);

    dim3 ggrid((N_NODES + 63) / 64, 2);                  // (782, 2)
    half_gemm<<<ggrid, 512, 0, stream>>>(mean, x, wn, wsf, bias, out);
}

// Round 5
// 204.480 us; speedup vs baseline: 3.7567x; 3.4140x over previous
//
#include <hip/hip_runtime.h>
#include <hip/hip_bf16.h>

#define N_NODES 50000
#define N_EDGES 800000
#define N_FEAT  64
#define UNITS   128
#define OUT_C   256
#define MAXDEG  64

// ---------------------------------------------------------------------------
// Kernel 0: detect int64 vs int32 edge_index (odd words all zero => int64).
// ---------------------------------------------------------------------------
__global__ void detect_idx_dtype(const void* __restrict__ ei_raw,
                                 int* __restrict__ flag)
{
    const int* p = (const int*)ei_raw;
    int v = p[2 * threadIdx.x + 1];
    unsigned long long b = __ballot(v == 0);
    if (threadIdx.x == 0) *flag = (b == ~0ull) ? 1 : 0;
}

// ---------------------------------------------------------------------------
// Kernel 1: bucket fill. adj[row][pos] = col, pos = cursor[row]++.
// Fixed-stride buckets (MAXDEG=64): no histogram, no scan. Max degree of
// Binomial(800k, 1/50k) ~ 38; pos clamped for safety. col < 65536 -> u16.
// ---------------------------------------------------------------------------
__global__ __launch_bounds__(256) void bucket_fill(
    const void* __restrict__ ei_raw, const int* __restrict__ flag,
    int* __restrict__ cursor, unsigned short* __restrict__ adj)
{
    int e = blockIdx.x * blockDim.x + threadIdx.x;
    if (e >= N_EDGES) return;
    int row, col;
    if (*flag) {
        row = (int)((const long long*)ei_raw)[e];
        col = (int)((const long long*)ei_raw)[(long long)N_EDGES + e];
    } else {
        row = ((const int*)ei_raw)[e];
        col = ((const int*)ei_raw)[N_EDGES + e];
    }
    row = min(max(row, 0), N_NODES - 1);
    col = min(max(col, 0), N_NODES - 1);
    int pos = atomicAdd(&cursor[row], 1);
    if (pos < MAXDEG) adj[row * MAXDEG + pos] = (unsigned short)col;
}

// ---------------------------------------------------------------------------
// Kernel 2: gather-aggregate. One wave per node; lane = feature. Each
// x-row load is a fully-coalesced 256B wave read; 4 independent partial
// sums for load ILP. No atomics.
// ---------------------------------------------------------------------------
__global__ __launch_bounds__(256) void aggregate(
    const float* __restrict__ x, const int* __restrict__ cursor,
    const unsigned short* __restrict__ adj, float* __restrict__ mean)
{
    int wv   = (blockIdx.x * blockDim.x + threadIdx.x) >> 6;
    int lane = threadIdx.x & 63;
    if (wv >= N_NODES) return;
    int deg = min(cursor[wv], MAXDEG);
    const unsigned short* a = &adj[wv * MAXDEG];

    float s0 = 0.f, s1 = 0.f, s2 = 0.f, s3 = 0.f;
    int j = 0;
    for (; j + 4 <= deg; j += 4) {
        ushort4 n = *(const ushort4*)&a[j];     // wave-uniform 8B load
        float v0 = x[(int)n.x * N_FEAT + lane];
        float v1 = x[(int)n.y * N_FEAT + lane];
        float v2 = x[(int)n.z * N_FEAT + lane];
        float v3 = x[(int)n.w * N_FEAT + lane];
        s0 += v0; s1 += v1; s2 += v2; s3 += v3;
    }
    for (; j < deg; ++j) s0 += x[(int)a[j] * N_FEAT + lane];
    float s = (s0 + s1) + (s2 + s3);
    mean[wv * N_FEAT + lane] = s / fmaxf((float)deg, 1.0f);
}

// ---------------------------------------------------------------------------
// Kernel 3: half-GEMM [32 rows] x [64][128] + bias + relu.
// blockIdx.y = 0: mean @ wn -> out cols 0..127;  = 1: x @ wsf -> 128..255.
// 256 threads; thread (cg=t&31 -> 4 cols, r0=(t>>5)*4 -> 4 rows).
// LDS 40KB (W 32KB + A 8KB) -> 4 blocks/CU. Register budget deliberately
// small (acc 16 + w 4 + a 4 ~= 40 VGPR) and k-loop only unroll-4 so the
// scheduler cannot hoist enough LDS loads to spill (rounds 3+4 post-mortem:
// full unroll at 128-VGPR cap => 800MB scratch traffic).
// Staging bounds: W = 2048 float4 (8/thread), A = 512 float4 (2/thread).
// ---------------------------------------------------------------------------
#define FMA4(ACC, AV, W) \
    ACC.x += (AV) * (W).x; ACC.y += (AV) * (W).y; \
    ACC.z += (AV) * (W).z; ACC.w += (AV) * (W).w;

#define G_ROWS 32

__global__ __launch_bounds__(256, 4) void half_gemm(
    const float* __restrict__ mean,   // [N][64]
    const float* __restrict__ x,      // [N][64]
    const float* __restrict__ wn,     // [64][128]
    const float* __restrict__ wsf,    // [64][128]
    const float* __restrict__ bias,   // [256]
    float* __restrict__ out)          // [N][256]
{
    __shared__ float W[N_FEAT * UNITS];   // 32 KB
    __shared__ float A[G_ROWS * N_FEAT];  // 8 KB

    const int t = threadIdx.x;
    const int half = blockIdx.y;
    const int row0 = blockIdx.x * G_ROWS;
    const float* __restrict__ src  = half ? x   : mean;
    const float* __restrict__ wsrc = half ? wsf : wn;

    // Stage W: 2048 float4 total, 8 per thread, coalesced.
    {
        const float4* w4 = (const float4*)wsrc;
        float4* W4 = (float4*)W;
        #pragma unroll
        for (int i = 0; i < 8; ++i) W4[t + 256 * i] = w4[t + 256 * i];
    }
    // Stage A: 512 float4 total, 2 per thread.
    {
        float4* A4 = (float4*)A;
        #pragma unroll
        for (int i = 0; i < 2; ++i) {
            int idx = t + 256 * i;
            int r = idx >> 4, k4 = idx & 15;
            int grow = row0 + r;
            float4 v = make_float4(0.f, 0.f, 0.f, 0.f);
            if (grow < N_NODES) v = *(const float4*)&src[grow * N_FEAT + k4 * 4];
            A4[idx] = v;
        }
    }
    __syncthreads();

    const int cg = t & 31;          // cols [cg*4, cg*4+4)
    const int r0 = (t >> 5) * 4;    // rows [r0, r0+4)
    const float4* W4 = (const float4*)W;   // [64 k][32 colgrp]

    float4 acc0 = make_float4(0.f, 0.f, 0.f, 0.f);
    float4 acc1 = acc0, acc2 = acc0, acc3 = acc0;

    #pragma unroll 4
    for (int k = 0; k < N_FEAT; ++k) {
        float4 w = W4[k * 32 + cg];               // per-lane b128, conflict-free
        float a0 = A[(r0 + 0) * N_FEAT + k];      // wave-broadcast b32
        float a1 = A[(r0 + 1) * N_FEAT + k];
        float a2 = A[(r0 + 2) * N_FEAT + k];
        float a3 = A[(r0 + 3) * N_FEAT + k];
        FMA4(acc0, a0, w)
        FMA4(acc1, a1, w)
        FMA4(acc2, a2, w)
        FMA4(acc3, a3, w)
    }

    float4 b = *(const float4*)&bias[half * UNITS + cg * 4];
    const int cbase = half * UNITS + cg * 4;
    int grow;
    float4 o;
    grow = row0 + r0 + 0;
    if (grow < N_NODES) {
        o.x = fmaxf(acc0.x + b.x, 0.f); o.y = fmaxf(acc0.y + b.y, 0.f);
        o.z = fmaxf(acc0.z + b.z, 0.f); o.w = fmaxf(acc0.w + b.w, 0.f);
        *(float4*)&out[(long long)grow * OUT_C + cbase] = o;
    }
    grow = row0 + r0 + 1;
    if (grow < N_NODES) {
        o.x = fmaxf(acc1.x + b.x, 0.f); o.y = fmaxf(acc1.y + b.y, 0.f);
        o.z = fmaxf(acc1.z + b.z, 0.f); o.w = fmaxf(acc1.w + b.w, 0.f);
        *(float4*)&out[(long long)grow * OUT_C + cbase] = o;
    }
    grow = row0 + r0 + 2;
    if (grow < N_NODES) {
        o.x = fmaxf(acc2.x + b.x, 0.f); o.y = fmaxf(acc2.y + b.y, 0.f);
        o.z = fmaxf(acc2.z + b.z, 0.f); o.w = fmaxf(acc2.w + b.w, 0.f);
        *(float4*)&out[(long long)grow * OUT_C + cbase] = o;
    }
    grow = row0 + r0 + 3;
    if (grow < N_NODES) {
        o.x = fmaxf(acc3.x + b.x, 0.f); o.y = fmaxf(acc3.y + b.y, 0.f);
        o.z = fmaxf(acc3.z + b.z, 0.f); o.w = fmaxf(acc3.w + b.w, 0.f);
        *(float4*)&out[(long long)grow * OUT_C + cbase] = o;
    }
}

// ---------------------------------------------------------------------------
extern "C" void kernel_launch(void* const* d_in, const int* in_sizes, int n_in,
                              void* d_out, int out_size, void* d_ws, size_t ws_size,
                              hipStream_t stream) {
    const float* x    = (const float*)d_in[0];
    const void*  ei   = d_in[1];                 // int64 or int32 [2][E]
    const float* wn   = (const float*)d_in[2];
    const float* wsf  = (const float*)d_in[3];
    const float* bias = (const float*)d_in[4];
    float*       out  = (float*)d_out;

    // Workspace (~19.4 MB): mean f32[50000*64] | adj u16[50000*64] |
    // cursor i32[50000] | flag i32.
    float*          mean   = (float*)d_ws;
    unsigned short* adj    = (unsigned short*)(mean + (size_t)N_NODES * N_FEAT);
    int*            cursor = (int*)(adj + (size_t)N_NODES * MAXDEG);
    int*            flag   = cursor + N_NODES;

    hipMemsetAsync(cursor, 0, (size_t)N_NODES * sizeof(int), stream);
    detect_idx_dtype<<<1, 64, 0, stream>>>(ei, flag);

    int eblocks = (N_EDGES + 255) / 256;                 // 3125
    bucket_fill<<<eblocks, 256, 0, stream>>>(ei, flag, cursor, adj);

    int ablocks = (N_NODES * 64 + 255) / 256;            // 12500 (wave/node)
    aggregate<<<ablocks, 256, 0, stream>>>(x, cursor, adj, mean);

    dim3 ggrid((N_NODES + G_ROWS - 1) / G_ROWS, 2);      // (1563, 2)
    half_gemm<<<ggrid, 256, 0, stream>>>(mean, x, wn, wsf, bias, out);
}

// Round 7
// 187.820 us; speedup vs baseline: 4.0899x; 1.0887x over previous
//
#include <hip/hip_runtime.h>
#include <hip/hip_bf16.h>

#define N_NODES 50000
#define N_EDGES 800000
#define N_FEAT  64
#define UNITS   128
#define OUT_C   256
#define MAXDEG  64
#define NPART   8          // one partition per XCD
#define ROWS_PER_PART 6250 // 50000 / 8

// ---------------------------------------------------------------------------
// Kernel 0: detect int64 vs int32 edge_index (odd words all zero => int64).
// ---------------------------------------------------------------------------
__global__ void detect_idx_dtype(const void* __restrict__ ei_raw,
                                 int* __restrict__ flag)
{
    const int* p = (const int*)ei_raw;
    int v = p[2 * threadIdx.x + 1];
    unsigned long long b = __ballot(v == 0);
    if (threadIdx.x == 0) *flag = (b == ~0ull) ? 1 : 0;
}

// ---------------------------------------------------------------------------
// Kernel 1: XCD-partitioned bucket fill. Round-5 counters showed 44.5 MB
// HBM write for 1.6 MB of payload: random 2B stores + cursor atomics made
// adj/cursor lines ping-pong between the 8 non-coherent XCD L2s. Fix:
// partition rows by row/6250; block's partition = blockIdx.x & 7, which
// under round-robin block->XCD dispatch pins each partition's lines to one
// XCD's L2 (adj slice 800KB + cursor 25KB both L2-resident). Each chunk of
// 256 edges is read by 8 blocks (row array re-reads are L3-served); only
// the matching ~1/8 of threads loads col and writes.
// ---------------------------------------------------------------------------
__global__ __launch_bounds__(256) void bucket_fill(
    const void* __restrict__ ei_raw, const int* __restrict__ flag,
    int* __restrict__ cursor, unsigned short* __restrict__ adj)
{
    int my_p  = blockIdx.x & (NPART - 1);
    int chunk = blockIdx.x >> 3;
    int e = chunk * 256 + threadIdx.x;
    if (e >= N_EDGES) return;

    int is64 = *flag;
    int row;
    if (is64) row = (int)((const long long*)ei_raw)[e];
    else      row = ((const int*)ei_raw)[e];
    row = min(max(row, 0), N_NODES - 1);

    if (row / ROWS_PER_PART != my_p) return;

    int col;
    if (is64) col = (int)((const long long*)ei_raw)[(long long)N_EDGES + e];
    else      col = ((const int*)ei_raw)[N_EDGES + e];
    col = min(max(col, 0), N_NODES - 1);

    int pos = atomicAdd(&cursor[row], 1);
    if (pos < MAXDEG) adj[row * MAXDEG + pos] = (unsigned short)col;
}

// ---------------------------------------------------------------------------
// Kernel 2: gather-aggregate. One wave per node; lane = feature. Each
// x-row load is a fully-coalesced 256B wave read; 4 independent partial
// sums for load ILP. No atomics.
// ---------------------------------------------------------------------------
__global__ __launch_bounds__(256) void aggregate(
    const float* __restrict__ x, const int* __restrict__ cursor,
    const unsigned short* __restrict__ adj, float* __restrict__ mean)
{
    int wv   = (blockIdx.x * blockDim.x + threadIdx.x) >> 6;
    int lane = threadIdx.x & 63;
    if (wv >= N_NODES) return;
    int deg = min(cursor[wv], MAXDEG);
    const unsigned short* a = &adj[wv * MAXDEG];

    float s0 = 0.f, s1 = 0.f, s2 = 0.f, s3 = 0.f;
    int j = 0;
    for (; j + 4 <= deg; j += 4) {
        ushort4 n = *(const ushort4*)&a[j];     // wave-uniform 8B load
        float v0 = x[(int)n.x * N_FEAT + lane];
        float v1 = x[(int)n.y * N_FEAT + lane];
        float v2 = x[(int)n.z * N_FEAT + lane];
        float v3 = x[(int)n.w * N_FEAT + lane];
        s0 += v0; s1 += v1; s2 += v2; s3 += v3;
    }
    for (; j < deg; ++j) s0 += x[(int)a[j] * N_FEAT + lane];
    float s = (s0 + s1) + (s2 + s3);
    mean[wv * N_FEAT + lane] = s / fmaxf((float)deg, 1.0f);
}

// ---------------------------------------------------------------------------
// Kernel 3: half-GEMM [32 rows] x [64][128] + bias + relu.
// blockIdx.y = 0: mean @ wn -> out cols 0..127;  = 1: x @ wsf -> 128..255.
// 256 threads; thread (cg=t&31 -> 4 cols, r0=(t>>5)*4 -> 4 rows).
// LDS 40KB (W 32KB + A 8KB) -> 4 blocks/CU. Register budget deliberately
// small and k-loop only unroll-4 so the scheduler cannot hoist enough LDS
// loads to spill (rounds 3+4 post-mortem: full unroll => 800MB scratch).
// ---------------------------------------------------------------------------
#define FMA4(ACC, AV, W) \
    ACC.x += (AV) * (W).x; ACC.y += (AV) * (W).y; \
    ACC.z += (AV) * (W).z; ACC.w += (AV) * (W).w;

#define G_ROWS 32

__global__ __launch_bounds__(256, 4) void half_gemm(
    const float* __restrict__ mean,   // [N][64]
    const float* __restrict__ x,      // [N][64]
    const float* __restrict__ wn,     // [64][128]
    const float* __restrict__ wsf,    // [64][128]
    const float* __restrict__ bias,   // [256]
    float* __restrict__ out)          // [N][256]
{
    __shared__ float W[N_FEAT * UNITS];   // 32 KB
    __shared__ float A[G_ROWS * N_FEAT];  // 8 KB

    const int t = threadIdx.x;
    const int half = blockIdx.y;
    const int row0 = blockIdx.x * G_ROWS;
    const float* __restrict__ src  = half ? x   : mean;
    const float* __restrict__ wsrc = half ? wsf : wn;

    // Stage W: 2048 float4 total, 8 per thread, coalesced.
    {
        const float4* w4 = (const float4*)wsrc;
        float4* W4 = (float4*)W;
        #pragma unroll
        for (int i = 0; i < 8; ++i) W4[t + 256 * i] = w4[t + 256 * i];
    }
    // Stage A: 512 float4 total, 2 per thread.
    {
        float4* A4 = (float4*)A;
        #pragma unroll
        for (int i = 0; i < 2; ++i) {
            int idx = t + 256 * i;
            int r = idx >> 4, k4 = idx & 15;
            int grow = row0 + r;
            float4 v = make_float4(0.f, 0.f, 0.f, 0.f);
            if (grow < N_NODES) v = *(const float4*)&src[grow * N_FEAT + k4 * 4];
            A4[idx] = v;
        }
    }
    __syncthreads();

    const int cg = t & 31;          // cols [cg*4, cg*4+4)
    const int r0 = (t >> 5) * 4;    // rows [r0, r0+4)
    const float4* W4 = (const float4*)W;   // [64 k][32 colgrp]

    float4 acc0 = make_float4(0.f, 0.f, 0.f, 0.f);
    float4 acc1 = acc0, acc2 = acc0, acc3 = acc0;

    #pragma unroll 4
    for (int k = 0; k < N_FEAT; ++k) {
        float4 w = W4[k * 32 + cg];               // per-lane b128, conflict-free
        float a0 = A[(r0 + 0) * N_FEAT + k];      // wave-broadcast b32
        float a1 = A[(r0 + 1) * N_FEAT + k];
        float a2 = A[(r0 + 2) * N_FEAT + k];
        float a3 = A[(r0 + 3) * N_FEAT + k];
        FMA4(acc0, a0, w)
        FMA4(acc1, a1, w)
        FMA4(acc2, a2, w)
        FMA4(acc3, a3, w)
    }

    float4 b = *(const float4*)&bias[half * UNITS + cg * 4];
    const int cbase = half * UNITS + cg * 4;
    int grow;
    float4 o;
    grow = row0 + r0 + 0;
    if (grow < N_NODES) {
        o.x = fmaxf(acc0.x + b.x, 0.f); o.y = fmaxf(acc0.y + b.y, 0.f);
        o.z = fmaxf(acc0.z + b.z, 0.f); o.w = fmaxf(acc0.w + b.w, 0.f);
        *(float4*)&out[(long long)grow * OUT_C + cbase] = o;
    }
    grow = row0 + r0 + 1;
    if (grow < N_NODES) {
        o.x = fmaxf(acc1.x + b.x, 0.f); o.y = fmaxf(acc1.y + b.y, 0.f);
        o.z = fmaxf(acc1.z + b.z, 0.f); o.w = fmaxf(acc1.w + b.w, 0.f);
        *(float4*)&out[(long long)grow * OUT_C + cbase] = o;
    }
    grow = row0 + r0 + 2;
    if (grow < N_NODES) {
        o.x = fmaxf(acc2.x + b.x, 0.f); o.y = fmaxf(acc2.y + b.y, 0.f);
        o.z = fmaxf(acc2.z + b.z, 0.f); o.w = fmaxf(acc2.w + b.w, 0.f);
        *(float4*)&out[(long long)grow * OUT_C + cbase] = o;
    }
    grow = row0 + r0 + 3;
    if (grow < N_NODES) {
        o.x = fmaxf(acc3.x + b.x, 0.f); o.y = fmaxf(acc3.y + b.y, 0.f);
        o.z = fmaxf(acc3.z + b.z, 0.f); o.w = fmaxf(acc3.w + b.w, 0.f);
        *(float4*)&out[(long long)grow * OUT_C + cbase] = o;
    }
}

// ---------------------------------------------------------------------------
extern "C" void kernel_launch(void* const* d_in, const int* in_sizes, int n_in,
                              void* d_out, int out_size, void* d_ws, size_t ws_size,
                              hipStream_t stream) {
    const float* x    = (const float*)d_in[0];
    const void*  ei   = d_in[1];                 // int64 or int32 [2][E]
    const float* wn   = (const float*)d_in[2];
    const float* wsf  = (const float*)d_in[3];
    const float* bias = (const float*)d_in[4];
    float*       out  = (float*)d_out;

    // Workspace (~19.4 MB): mean f32[50000*64] | adj u16[50000*64] |
    // cursor i32[50000] | flag i32.
    float*          mean   = (float*)d_ws;
    unsigned short* adj    = (unsigned short*)(mean + (size_t)N_NODES * N_FEAT);
    int*            cursor = (int*)(adj + (size_t)N_NODES * MAXDEG);
    int*            flag   = cursor + N_NODES;

    hipMemsetAsync(cursor, 0, (size_t)N_NODES * sizeof(int), stream);
    detect_idx_dtype<<<1, 64, 0, stream>>>(ei, flag);

    // Partitioned fill: 3125 chunks x 8 partitions.
    int eblocks = (N_EDGES + 255) / 256;                 // 3125
    bucket_fill<<<eblocks * NPART, 256, 0, stream>>>(ei, flag, cursor, adj);

    int ablocks = (N_NODES * 64 + 255) / 256;            // 12500 (wave/node)
    aggregate<<<ablocks, 256, 0, stream>>>(x, cursor, adj, mean);

    dim3 ggrid((N_NODES + G_ROWS - 1) / G_ROWS, 2);      // (1563, 2)
    half_gemm<<<ggrid, 256, 0, stream>>>(mean, x, wn, wsf, bias, out);
}